// Round 20
// baseline (175.116 us; speedup 1.0000x reference)
//
#include <hip/hip_runtime.h>
#include <hip/hip_bf16.h>
#include <math.h>

#define NROW 6144
#define LRELU_ALPHA 0.2f
#define MAXD 128   // padded CSR row capacity; mean nnz 62.4, sigma 7.8 -> ~8.3 sigma headroom

typedef __attribute__((ext_vector_type(2))) __bf16 bf16x2;
typedef __attribute__((ext_vector_type(4))) __bf16 bf16x4;
typedef __attribute__((ext_vector_type(8))) __bf16 bf16x8;
typedef __attribute__((ext_vector_type(16))) float f32x16;

// ---------------- prep_scan: adj bitmap (blocks 0..6143) + weight split (672)
// + wsa/wna dots (4) + x split to bf16 hi/lo planes (3072). Register-light.
__global__ __launch_bounds__(256) void prep_scan(
    const float* __restrict__ adj, uint32_t* __restrict__ bm,
    const float* __restrict__ W1, const float* __restrict__ W2, const float* __restrict__ W3,
    __bf16* __restrict__ w1h, __bf16* __restrict__ w1l,
    __bf16* __restrict__ w2h, __bf16* __restrict__ w2l,
    __bf16* __restrict__ w3h, __bf16* __restrict__ w3l,
    const float* __restrict__ as1, const float* __restrict__ an1,
    const float* __restrict__ as2, const float* __restrict__ an2,
    const float* __restrict__ as3, const float* __restrict__ an3,
    float* __restrict__ wsa1, float* __restrict__ wna1,
    float* __restrict__ wsa2, float* __restrict__ wna2,
    float* __restrict__ wsa3, float* __restrict__ wna3,
    const float* __restrict__ x, __bf16* __restrict__ xh, __bf16* __restrict__ xl) {
  int b = blockIdx.x;
  if (b < NROW) {
    const int id = b * 256 + threadIdx.x;
    const int row = id >> 8, sub = id & 255;
    const float4* ap = (const float4*)(adj + (size_t)row * NROW) + (sub >> 6) * 384 + (sub & 63);
    uint32_t mk = 0;
#pragma unroll
    for (int it = 0; it < 6; ++it) {
      float4 a = ap[it * 64];
      uint32_t q = (uint32_t)(a.x > 0.f) | ((uint32_t)(a.y > 0.f) << 1) |
                   ((uint32_t)(a.z > 0.f) << 2) | ((uint32_t)(a.w > 0.f) << 3);
      mk |= q << (it * 4);
    }
    bm[id] = mk;
    return;
  }
  b -= NROW;
  if (b < 672) {
    int idx = b * 256 + threadIdx.x;
    const float* W; __bf16 *wh, *wl; int K, D;
    if (idx < 131072) { W = W1; wh = w1h; wl = w1l; K = 512; D = 256; }
    else if (idx < 163840) { idx -= 131072; W = W2; wh = w2h; wl = w2l; K = 256; D = 128; }
    else { idx -= 163840; if (idx >= 8192) return; W = W3; wh = w3h; wl = w3l; K = 128; D = 64; }
    int k = idx / D, d = idx - k * D;
    float v = W[idx];
    __bf16 h = (__bf16)v;
    wh[(size_t)d * K + k] = h;
    wl[(size_t)d * K + k] = (__bf16)(v - (float)h);
    return;
  }
  b -= 672;
  if (b < 4) {
    int t = b * 256 + threadIdx.x;
    if (t < 512) {
      float s = 0.f, n = 0.f;
      for (int d = 0; d < 256; ++d) { float w = W1[t * 256 + d]; s = fmaf(w, as1[d], s); n = fmaf(w, an1[d], n); }
      wsa1[t] = s; wna1[t] = n;
    } else if (t < 768) {
      int k = t - 512;
      float s = 0.f, n = 0.f;
      for (int d = 0; d < 128; ++d) { float w = W2[k * 128 + d]; s = fmaf(w, as2[d], s); n = fmaf(w, an2[d], n); }
      wsa2[k] = s; wna2[k] = n;
    } else if (t < 896) {
      int k = t - 768;
      float s = 0.f, n = 0.f;
      for (int d = 0; d < 64; ++d) { float w = W3[k * 64 + d]; s = fmaf(w, as3[d], s); n = fmaf(w, an3[d], n); }
      wsa3[k] = s; wna3[k] = n;
    }
    return;
  }
  // x split: 6144*512 f32 -> xh/xl bf16 planes, 4 elems/thread
  const int idx = (b - 4) * 256 + threadIdx.x;
  float4 v = ((const float4*)x)[idx];
  __bf16 h0 = (__bf16)v.x, h1 = (__bf16)v.y, h2 = (__bf16)v.z, h3 = (__bf16)v.w;
  bf16x4 hv = {h0, h1, h2, h3};
  bf16x4 lv = {(__bf16)(v.x - (float)h0), (__bf16)(v.y - (float)h1),
               (__bf16)(v.z - (float)h2), (__bf16)(v.w - (float)h3)};
  *(bf16x4*)&xh[(size_t)idx * 4] = hv;
  *(bf16x4*)&xl[(size_t)idx * 4] = lv;
}

// ---------------- csr_from_bitmap: one block per row
__global__ __launch_bounds__(256) void csr_from_bitmap(const uint32_t* __restrict__ bm,
                                                       const float* __restrict__ Mm,
                                                       int* __restrict__ cnt,
                                                       int* __restrict__ cidx,
                                                       float* __restrict__ cmval) {
  const int row = blockIdx.x;
  const int tid = threadIdx.x, wv = tid >> 6, lane = tid & 63;
  __shared__ int wtot[4];
  __shared__ int jsh[MAXD];
  const uint32_t mask = bm[row * 256 + tid];
  const int pc = __popc(mask);
  int pre = pc;
#pragma unroll
  for (int off = 1; off < 64; off <<= 1) {
    int t = __shfl_up(pre, off);
    if (lane >= off) pre += t;
  }
  if (lane == 63) wtot[wv] = pre;
  __syncthreads();
  int base = pre - pc;
  for (int w = 0; w < wv; ++w) base += wtot[w];
  const int total = min(wtot[0] + wtot[1] + wtot[2] + wtot[3], MAXD);
  uint32_t m = mask;
  int p = base;
  const int cb0 = wv * 1536 + lane * 4;
  while (m) {
    int bit = __ffs(m) - 1;
    m &= m - 1;
    if (p < MAXD) jsh[p] = cb0 + ((bit >> 2) << 8) + (bit & 3);
    ++p;
  }
  __syncthreads();
  const float* mrow = Mm + (size_t)row * NROW;
  for (int k = tid; k < total; k += 256) {
    int j = jsh[k];
    cidx[(size_t)row * MAXD + k] = j;
    cmval[(size_t)row * MAXD + k] = mrow[j];
  }
  if (tid == 0) cnt[row] = total;
}

// ---------------- gemm_bf: A pre-split bf16 hi/lo (conversion-free staging:
// pure bf16x8 loads + ds_write_b128) x intra-block split-K (r19 structure).
// 32x32 tile, 4 waves each take one 16-wide kk slice, LDS reduce.
// + fused sv/nv (from ah+al). C (f32) / Cb (bf16 hi) nullable. Deterministic.
__global__ __launch_bounds__(256) void gemm_bf(
    const __bf16* __restrict__ Ath, const __bf16* __restrict__ Atl,
    const __bf16* __restrict__ Bth, const __bf16* __restrict__ Btl,
    const float* __restrict__ wsa, const float* __restrict__ wna,
    float* __restrict__ sv, float* __restrict__ nv,
    float* __restrict__ C, __bf16* __restrict__ Cb, int K, int D) {
  __shared__ __bf16 Ah[32][72], Al[32][72], Bh[32][72], Bl[32][72];  // 18 KB
  __shared__ float reds[3][16][64];                                  // 12 KB
  __shared__ float svs[4][32], nvs[4][32];
  const int tid = threadIdx.x;
  const int wv = tid >> 6, lane = tid & 63;
  const int l31 = lane & 31, lh = lane >> 5;
  const int rb = blockIdx.x * 32, jb = blockIdx.y * 32;
  const bool do_sn = (blockIdx.y == 0);
  const int srow = tid >> 3, scq = (tid & 7) * 8;
  f32x16 acc;
#pragma unroll
  for (int r = 0; r < 16; ++r) acc[r] = 0.f;
  float ss = 0.f, nn = 0.f;
  for (int kt = 0; kt < K; kt += 64) {
    // stage A and B: pure vector loads + b128 LDS writes (no conversion)
    *(bf16x8*)&Ah[srow][scq] = *(const bf16x8*)(Ath + (size_t)(rb + srow) * K + kt + scq);
    *(bf16x8*)&Al[srow][scq] = *(const bf16x8*)(Atl + (size_t)(rb + srow) * K + kt + scq);
    *(bf16x8*)&Bh[srow][scq] = *(const bf16x8*)(Bth + (size_t)(jb + srow) * K + kt + scq);
    *(bf16x8*)&Bl[srow][scq] = *(const bf16x8*)(Btl + (size_t)(jb + srow) * K + kt + scq);
    __syncthreads();
    // each wave consumes its own 16-wide kk slice (intra-block split-K)
    {
      bf16x8 af  = *(const bf16x8*)&Ah[l31][wv * 16 + lh * 8];
      bf16x8 alf = *(const bf16x8*)&Al[l31][wv * 16 + lh * 8];
      bf16x8 bhf = *(const bf16x8*)&Bh[l31][wv * 16 + lh * 8];
      bf16x8 blf = *(const bf16x8*)&Bl[l31][wv * 16 + lh * 8];
      if (do_sn) {
        const float* wsp = wsa + kt + wv * 16 + lh * 8;
        const float* wnp = wna + kt + wv * 16 + lh * 8;
#pragma unroll
        for (int t = 0; t < 8; ++t) {
          float av = (float)af[t] + (float)alf[t];
          ss = fmaf(av, wsp[t], ss);
          nn = fmaf(av, wnp[t], nn);
        }
      }
      acc = __builtin_amdgcn_mfma_f32_32x32x16_bf16(af, bhf, acc, 0, 0, 0);
      acc = __builtin_amdgcn_mfma_f32_32x32x16_bf16(af, blf, acc, 0, 0, 0);
      acc = __builtin_amdgcn_mfma_f32_32x32x16_bf16(alf, bhf, acc, 0, 0, 0);
    }
    __syncthreads();
  }
  // combine the 4 per-wave K-partials
  if (wv > 0) {
#pragma unroll
    for (int r = 0; r < 16; ++r) reds[wv - 1][r][lane] = acc[r];
  }
  if (do_sn) {
    ss += __shfl_xor(ss, 32);
    nn += __shfl_xor(nn, 32);
    if (lh == 0) { svs[wv][l31] = ss; nvs[wv][l31] = nn; }
  }
  __syncthreads();
  if (wv == 0) {
#pragma unroll
    for (int w = 0; w < 3; ++w)
#pragma unroll
      for (int r = 0; r < 16; ++r) acc[r] += reds[w][r][lane];
    if (do_sn && lh == 0) {
      float s = 0.f, n = 0.f;
#pragma unroll
      for (int w = 0; w < 4; ++w) { s += svs[w][l31]; n += nvs[w][l31]; }
      sv[rb + l31] = s;
      nv[rb + l31] = n;
    }
    // C/D layout: col = lane&31, row = (reg&3) + 8*(reg>>2) + 4*(lane>>5)
#pragma unroll
    for (int r = 0; r < 16; ++r) {
      int rowi = (r & 3) + 8 * (r >> 2) + 4 * lh;
      int col = jb + l31;
      if (C)  C[(size_t)(rb + rowi) * D + col] = acc[r];
      if (Cb) Cb[(size_t)(rb + rowi) * D + col] = (__bf16)acc[r];
    }
  }
}

// ---------------- CSR masked-softmax attention + att@h + elu.
// BF16G: gather from bf16 h (2 cols/lane), emit bf16 hi/lo output planes
// (next gemm's A operand). NORM (D=64, f32 gather): normalize -> z, zb.
template <int D, int WPR, bool BF16G, bool NORM>
__global__ __launch_bounds__(256) void attn_csr(const float* __restrict__ h,
                                                const __bf16* __restrict__ hb,
                                                const int* __restrict__ cnt,
                                                const int* __restrict__ cidx,
                                                const float* __restrict__ cmval,
                                                const float* __restrict__ sv,
                                                const float* __restrict__ nv,
                                                float* __restrict__ out,
                                                __bf16* __restrict__ outh,
                                                __bf16* __restrict__ outl,
                                                __bf16* __restrict__ zb) {
  constexpr int RPB = 4 / WPR;
  constexpr int CW = D / WPR;
  constexpr int NQ = BF16G ? 2 : CW / 64;
  __shared__ float ws[4][MAXD];
  __shared__ int js[4][MAXD];
  const int wv = threadIdx.x >> 6, lane = threadIdx.x & 63;
  const int row = blockIdx.x * RPB + wv / WPR;
  const int half = wv % WPR;
  const int c = cnt[row];
  const float si = sv[row];
  const size_t cb = (size_t)row * MAXD;

  float e0 = -1e30f, e1 = -1e30f;
  int j0 = 0, j1 = 0;
  if (lane < c) {
    j0 = cidx[cb + lane];
    float v = (si + nv[j0]) * cmval[cb + lane];
    e0 = v > 0.f ? v : LRELU_ALPHA * v;
  }
  if (lane + 64 < c) {
    j1 = cidx[cb + lane + 64];
    float v = (si + nv[j1]) * cmval[cb + lane + 64];
    e1 = v > 0.f ? v : LRELU_ALPHA * v;
  }
  float mx = fmaxf(e0, e1);
#pragma unroll
  for (int off = 32; off; off >>= 1) mx = fmaxf(mx, __shfl_xor(mx, off));
  float w0 = lane < c ? __expf(e0 - mx) : 0.f;
  float w1 = lane + 64 < c ? __expf(e1 - mx) : 0.f;
  float s = w0 + w1;
#pragma unroll
  for (int off = 32; off; off >>= 1) s += __shfl_xor(s, off);
  const float inv = 1.f / s;
  ws[wv][lane] = w0 * inv;
  ws[wv][lane + 64] = w1 * inv;
  js[wv][lane] = j0;
  js[wv][lane + 64] = j1;
  // intra-wave LDS write->read: single-wave coherence, no barrier
  const int cbase = half * CW;
  float acc[NQ];
#pragma unroll
  for (int q = 0; q < NQ; ++q) acc[q] = 0.f;
  if (BF16G) {
#pragma unroll 8
    for (int k = 0; k < c; ++k) {
      const float wk = ws[wv][k];
      const uint32_t* hr = (const uint32_t*)(hb + (size_t)js[wv][k] * D + cbase);
      uint32_t v = hr[lane];
      acc[0] = fmaf(wk, __uint_as_float(v << 16), acc[0]);
      acc[1] = fmaf(wk, __uint_as_float(v & 0xffff0000u), acc[1]);
    }
    float ox = acc[0] > 0.f ? acc[0] : expm1f(acc[0]);
    float oy = acc[1] > 0.f ? acc[1] : expm1f(acc[1]);
    __bf16 h0 = (__bf16)ox, h1 = (__bf16)oy;
    bf16x2 hv = {h0, h1};
    bf16x2 lv = {(__bf16)(ox - (float)h0), (__bf16)(oy - (float)h1)};
    *(bf16x2*)&outh[(size_t)row * D + cbase + lane * 2] = hv;
    *(bf16x2*)&outl[(size_t)row * D + cbase + lane * 2] = lv;
  } else {
#pragma unroll 8
    for (int k = 0; k < c; ++k) {
      const float wk = ws[wv][k];
      const float* hr = h + (size_t)js[wv][k] * D + cbase;
#pragma unroll
      for (int q = 0; q < NQ; ++q) acc[q] = fmaf(wk, hr[lane + q * 64], acc[q]);
    }
    if (!NORM) {
#pragma unroll
      for (int q = 0; q < NQ; ++q) {
        float a = acc[q];
        out[(size_t)row * D + cbase + lane + q * 64] = a > 0.f ? a : expm1f(a);
      }
    } else {
      float a = acc[0];
      a = a > 0.f ? a : expm1f(a);
      float sq = a * a;
#pragma unroll
      for (int off = 32; off; off >>= 1) sq += __shfl_xor(sq, off);
      float zv = a / fmaxf(sqrtf(sq), 1e-12f);
      out[(size_t)row * 64 + lane] = zv;
      zb[(size_t)row * 64 + lane] = (__bf16)zv;
    }
  }
}

// ---------------- A_pred = sigmoid(z @ z^T) via bf16 MFMA
__global__ __launch_bounds__(256) void decoder_mfma(const __bf16* __restrict__ zb,
                                                    float* __restrict__ out) {
  const int wv = threadIdx.x >> 6, lane = threadIdx.x & 63;
  const int ib = blockIdx.y * 64 + (wv >> 1) * 32;
  const int jb = blockIdx.x * 64 + (wv & 1) * 32;
  const int l31 = lane & 31, lh = lane >> 5;
  const __bf16* Arow = zb + (size_t)(ib + l31) * 64 + lh * 8;
  const __bf16* Brow = zb + (size_t)(jb + l31) * 64 + lh * 8;
  f32x16 acc;
#pragma unroll
  for (int r = 0; r < 16; ++r) acc[r] = 0.f;
#pragma unroll
  for (int kk = 0; kk < 4; ++kk) {
    bf16x8 af = *(const bf16x8*)(Arow + kk * 16);
    bf16x8 bfv = *(const bf16x8*)(Brow + kk * 16);
    acc = __builtin_amdgcn_mfma_f32_32x32x16_bf16(af, bfv, acc, 0, 0, 0);
  }
#pragma unroll
  for (int r = 0; r < 16; ++r) {
    int rowi = (r & 3) + 8 * (r >> 2) + 4 * lh;
    float v = 1.f / (1.f + __expf(-acc[r]));
    out[(size_t)(ib + rowi) * NROW + jb + l31] = v;
  }
}

extern "C" void kernel_launch(void* const* d_in, const int* in_sizes, int n_in,
                              void* d_out, int out_size, void* d_ws, size_t ws_size,
                              hipStream_t stream) {
  const float* x   = (const float*)d_in[0];
  const float* adj = (const float*)d_in[1];
  const float* Mm  = (const float*)d_in[2];
  const float* W1  = (const float*)d_in[3];
  const float* as1 = (const float*)d_in[4];
  const float* an1 = (const float*)d_in[5];
  const float* W2  = (const float*)d_in[6];
  const float* as2 = (const float*)d_in[7];
  const float* an2 = (const float*)d_in[8];
  const float* W3  = (const float*)d_in[9];
  const float* as3 = (const float*)d_in[10];
  const float* an3 = (const float*)d_in[11];

  float* out = (float*)d_out;
  float* z = out + (size_t)NROW * NROW;

  float* wsp = (float*)d_ws;
  float* hA   = wsp;                          // [N,256] (f32, layer-3 gather)
  float* sv   = hA + (size_t)NROW * 256;      // [N]
  float* nv   = sv + NROW;                    // [N]
  float* cmv  = nv + NROW;                    // [N,MAXD]
  int*   cix  = (int*)(cmv + (size_t)NROW * MAXD);  // [N,MAXD]
  int*   cct  = cix + (size_t)NROW * MAXD;    // [N]
  __bf16* zb  = (__bf16*)(cct + NROW);        // [N,64]
  __bf16* w1h = zb + (size_t)NROW * 64;       // split/transposed weights
  __bf16* w1l = w1h + 512 * 256;
  __bf16* w2h = w1l + 512 * 256;
  __bf16* w2l = w2h + 256 * 128;
  __bf16* w3h = w2l + 256 * 128;
  __bf16* w3l = w3h + 128 * 64;
  float* wsa1 = (float*)(w3l + 128 * 64);     // wsa/wna vectors
  float* wna1 = wsa1 + 512;
  float* wsa2 = wna1 + 512;
  float* wna2 = wsa2 + 256;
  float* wsa3 = wna2 + 256;
  float* wna3 = wsa3 + 128;
  __bf16* hAb = (__bf16*)(wna3 + 128);        // [N,256] gemm-out hi (gather src)
  uint32_t* bmp = (uint32_t*)(hAb + (size_t)NROW * 256);  // [N,256] adj bitmap
  __bf16* xh  = (__bf16*)(bmp + (size_t)NROW * 256);      // [N,512] x hi
  __bf16* xl  = xh + (size_t)NROW * 512;      // [N,512] x lo
  __bf16* hBh = xl + (size_t)NROW * 512;      // [N,256] attn-out hi
  __bf16* hBl = hBh + (size_t)NROW * 256;     // [N,256] attn-out lo

  dim3 b256(256);

  // 1. prep: bitmap scan + weight splits + wsa/wna dots + x split
  prep_scan<<<dim3(NROW + 676 + 3072), b256, 0, stream>>>(
      adj, bmp, W1, W2, W3, w1h, w1l, w2h, w2l, w3h, w3l,
      as1, an1, as2, an2, as3, an3, wsa1, wna1, wsa2, wna2, wsa3, wna3,
      x, xh, xl);

  // 2. CSR from bitmap (+ M gather)
  csr_from_bitmap<<<dim3(NROW), b256, 0, stream>>>(bmp, Mm, cct, cix, cmv);

  // 3-4. Layer 1: conversion-free bf16 gemm -> attn (emits bf16 hi/lo h)
  gemm_bf<<<dim3(NROW / 32, 256 / 32), b256, 0, stream>>>(xh, xl, w1h, w1l, wsa1, wna1, sv, nv, nullptr, hAb, 512, 256);
  attn_csr<256, 2, true, false><<<dim3(NROW / 2), b256, 0, stream>>>(nullptr, hAb, cct, cix, cmv, sv, nv, nullptr, hBh, hBl, nullptr);

  // 5-6. Layer 2
  gemm_bf<<<dim3(NROW / 32, 128 / 32), b256, 0, stream>>>(hBh, hBl, w2h, w2l, wsa2, wna2, sv, nv, nullptr, hAb, 256, 128);
  attn_csr<128, 1, true, false><<<dim3(NROW / 4), b256, 0, stream>>>(nullptr, hAb, cct, cix, cmv, sv, nv, nullptr, hBh, hBl, nullptr);

  // 7-8. Layer 3 (f32 h for gather+norm)
  gemm_bf<<<dim3(NROW / 32, 64 / 32), b256, 0, stream>>>(hBh, hBl, w3h, w3l, wsa3, wna3, sv, nv, hA, nullptr, 128, 64);
  attn_csr<64, 1, false, true><<<dim3(NROW / 4), b256, 0, stream>>>(hA, nullptr, cct, cix, cmv, sv, nv, z, nullptr, nullptr, zb);

  // 9. Decoder
  decoder_mfma<<<dim3(NROW / 64, NROW / 64), b256, 0, stream>>>(zb, out);
}

// Round 21
// 171.339 us; speedup vs baseline: 1.0220x; 1.0220x over previous
//
#include <hip/hip_runtime.h>
#include <hip/hip_bf16.h>
#include <math.h>

#define NROW 6144
#define LRELU_ALPHA 0.2f
#define MAXD 128   // padded CSR row capacity; mean nnz 62.4, sigma 7.8 -> ~8.3 sigma headroom

typedef __attribute__((ext_vector_type(8))) __bf16 bf16x8;
typedef __attribute__((ext_vector_type(16))) float f32x16;

// ---------------- prep_scan: adj bitmap (blocks 0..6143, pure streaming) +
// weight split/transpose (next 672) + wsa/wna dots (last 4). Register-light.
__global__ __launch_bounds__(256) void prep_scan(
    const float* __restrict__ adj, uint32_t* __restrict__ bm,
    const float* __restrict__ W1, const float* __restrict__ W2, const float* __restrict__ W3,
    __bf16* __restrict__ w1h, __bf16* __restrict__ w1l,
    __bf16* __restrict__ w2h, __bf16* __restrict__ w2l,
    __bf16* __restrict__ w3h, __bf16* __restrict__ w3l,
    const float* __restrict__ as1, const float* __restrict__ an1,
    const float* __restrict__ as2, const float* __restrict__ an2,
    const float* __restrict__ as3, const float* __restrict__ an3,
    float* __restrict__ wsa1, float* __restrict__ wna1,
    float* __restrict__ wsa2, float* __restrict__ wna2,
    float* __restrict__ wsa3, float* __restrict__ wna3) {
  int b = blockIdx.x;
  if (b < NROW) {
    const int id = b * 256 + threadIdx.x;
    const int row = id >> 8, sub = id & 255;
    const float4* ap = (const float4*)(adj + (size_t)row * NROW) + (sub >> 6) * 384 + (sub & 63);
    uint32_t mk = 0;
#pragma unroll
    for (int it = 0; it < 6; ++it) {
      float4 a = ap[it * 64];
      uint32_t q = (uint32_t)(a.x > 0.f) | ((uint32_t)(a.y > 0.f) << 1) |
                   ((uint32_t)(a.z > 0.f) << 2) | ((uint32_t)(a.w > 0.f) << 3);
      mk |= q << (it * 4);
    }
    bm[id] = mk;
    return;
  }
  b -= NROW;
  if (b < 672) {
    int idx = b * 256 + threadIdx.x;
    const float* W; __bf16 *wh, *wl; int K, D;
    if (idx < 131072) { W = W1; wh = w1h; wl = w1l; K = 512; D = 256; }
    else if (idx < 163840) { idx -= 131072; W = W2; wh = w2h; wl = w2l; K = 256; D = 128; }
    else { idx -= 163840; if (idx >= 8192) return; W = W3; wh = w3h; wl = w3l; K = 128; D = 64; }
    int k = idx / D, d = idx - k * D;
    float v = W[idx];
    __bf16 h = (__bf16)v;
    wh[(size_t)d * K + k] = h;
    wl[(size_t)d * K + k] = (__bf16)(v - (float)h);
    return;
  }
  int t = (b - 672) * 256 + threadIdx.x;
  if (t < 512) {
    float s = 0.f, n = 0.f;
    for (int d = 0; d < 256; ++d) { float w = W1[t * 256 + d]; s = fmaf(w, as1[d], s); n = fmaf(w, an1[d], n); }
    wsa1[t] = s; wna1[t] = n;
  } else if (t < 768) {
    int k = t - 512;
    float s = 0.f, n = 0.f;
    for (int d = 0; d < 128; ++d) { float w = W2[k * 128 + d]; s = fmaf(w, as2[d], s); n = fmaf(w, an2[d], n); }
    wsa2[k] = s; wna2[k] = n;
  } else if (t < 896) {
    int k = t - 768;
    float s = 0.f, n = 0.f;
    for (int d = 0; d < 64; ++d) { float w = W3[k * 64 + d]; s = fmaf(w, as3[d], s); n = fmaf(w, an3[d], n); }
    wsa3[k] = s; wna3[k] = n;
  }
}

// ---------------- csr_from_bitmap: one block per row
__global__ __launch_bounds__(256) void csr_from_bitmap(const uint32_t* __restrict__ bm,
                                                       const float* __restrict__ Mm,
                                                       int* __restrict__ cnt,
                                                       int* __restrict__ cidx,
                                                       float* __restrict__ cmval) {
  const int row = blockIdx.x;
  const int tid = threadIdx.x, wv = tid >> 6, lane = tid & 63;
  __shared__ int wtot[4];
  __shared__ int jsh[MAXD];
  const uint32_t mask = bm[row * 256 + tid];
  const int pc = __popc(mask);
  int pre = pc;
#pragma unroll
  for (int off = 1; off < 64; off <<= 1) {
    int t = __shfl_up(pre, off);
    if (lane >= off) pre += t;
  }
  if (lane == 63) wtot[wv] = pre;
  __syncthreads();
  int base = pre - pc;
  for (int w = 0; w < wv; ++w) base += wtot[w];
  const int total = min(wtot[0] + wtot[1] + wtot[2] + wtot[3], MAXD);
  uint32_t m = mask;
  int p = base;
  const int cb0 = wv * 1536 + lane * 4;
  while (m) {
    int bit = __ffs(m) - 1;
    m &= m - 1;
    if (p < MAXD) jsh[p] = cb0 + ((bit >> 2) << 8) + (bit & 3);
    ++p;
  }
  __syncthreads();
  const float* mrow = Mm + (size_t)row * NROW;
  for (int k = tid; k < total; k += 256) {
    int j = jsh[k];
    cidx[(size_t)row * MAXD + k] = j;
    cmval[(size_t)row * MAXD + k] = mrow[j];
  }
  if (tid == 0) cnt[row] = total;
}

// ---------------- gemm_lds2: LDS-staged (coalesced, r17) x intra-block
// split-K (r16). 32x32 output tile; per 64-K-step stage A(f32->bf16 hi/lo)
// + B into LDS, 4 waves each take one 16-wide kk slice; LDS reduce of the
// 4 partial accumulators. Grid (M/32, D/32). + fused sv/nv. Deterministic.
__global__ __launch_bounds__(256) void gemm_lds2(
    const float* __restrict__ A,
    const __bf16* __restrict__ Bth, const __bf16* __restrict__ Btl,
    const float* __restrict__ wsa, const float* __restrict__ wna,
    float* __restrict__ sv, float* __restrict__ nv,
    float* __restrict__ C, __bf16* __restrict__ Cb, int K, int D) {
  __shared__ __bf16 Ah[32][72], Al[32][72], Bh[32][72], Bl[32][72];  // 18 KB
  __shared__ float reds[3][16][64];                                  // 12 KB
  __shared__ float svs[4][32], nvs[4][32];
  const int tid = threadIdx.x;
  const int wv = tid >> 6, lane = tid & 63;
  const int l31 = lane & 31, lh = lane >> 5;
  const int rb = blockIdx.x * 32, jb = blockIdx.y * 32;
  const bool do_sn = (blockIdx.y == 0);
  f32x16 acc;
#pragma unroll
  for (int r = 0; r < 16; ++r) acc[r] = 0.f;
  float ss = 0.f, nn = 0.f;
  for (int kt = 0; kt < K; kt += 64) {
    // stage A: 32 rows x 64 cols f32, coalesced (16 lanes x 16B = 256B/row)
#pragma unroll
    for (int c2 = 0; c2 < 2; ++c2) {
      int flat = c2 * 256 + tid;
      int row = flat >> 4, cq = (flat & 15) * 4;
      float4 a = *(const float4*)(A + (size_t)(rb + row) * K + kt + cq);
      __bf16 h0 = (__bf16)a.x, h1 = (__bf16)a.y, h2 = (__bf16)a.z, h3 = (__bf16)a.w;
      Ah[row][cq] = h0; Ah[row][cq + 1] = h1; Ah[row][cq + 2] = h2; Ah[row][cq + 3] = h3;
      Al[row][cq] = (__bf16)(a.x - (float)h0);
      Al[row][cq + 1] = (__bf16)(a.y - (float)h1);
      Al[row][cq + 2] = (__bf16)(a.z - (float)h2);
      Al[row][cq + 3] = (__bf16)(a.w - (float)h3);
    }
    // stage B (bf16 hi/lo, [D][K] layout): 32 d-rows x 64 k-cols
    {
      int row = tid >> 3, cq = (tid & 7) * 8;
      *(bf16x8*)&Bh[row][cq] = *(const bf16x8*)(Bth + (size_t)(jb + row) * K + kt + cq);
      *(bf16x8*)&Bl[row][cq] = *(const bf16x8*)(Btl + (size_t)(jb + row) * K + kt + cq);
    }
    __syncthreads();
    // each wave consumes its own 16-wide kk slice (intra-block split-K)
    {
      bf16x8 af  = *(const bf16x8*)&Ah[l31][wv * 16 + lh * 8];
      bf16x8 alf = *(const bf16x8*)&Al[l31][wv * 16 + lh * 8];
      bf16x8 bhf = *(const bf16x8*)&Bh[l31][wv * 16 + lh * 8];
      bf16x8 blf = *(const bf16x8*)&Bl[l31][wv * 16 + lh * 8];
      if (do_sn) {
        const float* wsp = wsa + kt + wv * 16 + lh * 8;
        const float* wnp = wna + kt + wv * 16 + lh * 8;
#pragma unroll
        for (int t = 0; t < 8; ++t) {
          float av = (float)af[t] + (float)alf[t];
          ss = fmaf(av, wsp[t], ss);
          nn = fmaf(av, wnp[t], nn);
        }
      }
      acc = __builtin_amdgcn_mfma_f32_32x32x16_bf16(af, bhf, acc, 0, 0, 0);
      acc = __builtin_amdgcn_mfma_f32_32x32x16_bf16(af, blf, acc, 0, 0, 0);
      acc = __builtin_amdgcn_mfma_f32_32x32x16_bf16(alf, bhf, acc, 0, 0, 0);
    }
    __syncthreads();
  }
  // combine the 4 per-wave K-partials
  if (wv > 0) {
#pragma unroll
    for (int r = 0; r < 16; ++r) reds[wv - 1][r][lane] = acc[r];
  }
  if (do_sn) {
    ss += __shfl_xor(ss, 32);
    nn += __shfl_xor(nn, 32);
    if (lh == 0) { svs[wv][l31] = ss; nvs[wv][l31] = nn; }
  }
  __syncthreads();
  if (wv == 0) {
#pragma unroll
    for (int w = 0; w < 3; ++w)
#pragma unroll
      for (int r = 0; r < 16; ++r) acc[r] += reds[w][r][lane];
    if (do_sn && lh == 0) {
      float s = 0.f, n = 0.f;
#pragma unroll
      for (int w = 0; w < 4; ++w) { s += svs[w][l31]; n += nvs[w][l31]; }
      sv[rb + l31] = s;
      nv[rb + l31] = n;
    }
    // C/D layout: col = lane&31, row = (reg&3) + 8*(reg>>2) + 4*(lane>>5)
#pragma unroll
    for (int r = 0; r < 16; ++r) {
      int rowi = (r & 3) + 8 * (r >> 2) + 4 * lh;
      int col = jb + l31;
      if (C)  C[(size_t)(rb + rowi) * D + col] = acc[r];
      if (Cb) Cb[(size_t)(rb + rowi) * D + col] = (__bf16)acc[r];
    }
  }
}

// ---------------- CSR masked-softmax attention + att@h + elu
template <int D, int WPR, bool BF16G, bool NORM>
__global__ __launch_bounds__(256) void attn_csr(const float* __restrict__ h,
                                                const __bf16* __restrict__ hb,
                                                const int* __restrict__ cnt,
                                                const int* __restrict__ cidx,
                                                const float* __restrict__ cmval,
                                                const float* __restrict__ sv,
                                                const float* __restrict__ nv,
                                                float* __restrict__ out,
                                                __bf16* __restrict__ zb) {
  constexpr int RPB = 4 / WPR;
  constexpr int CW = D / WPR;
  constexpr int NQ = BF16G ? 2 : CW / 64;
  __shared__ float ws[4][MAXD];
  __shared__ int js[4][MAXD];
  const int wv = threadIdx.x >> 6, lane = threadIdx.x & 63;
  const int row = blockIdx.x * RPB + wv / WPR;
  const int half = wv % WPR;
  const int c = cnt[row];
  const float si = sv[row];
  const size_t cb = (size_t)row * MAXD;

  float e0 = -1e30f, e1 = -1e30f;
  int j0 = 0, j1 = 0;
  if (lane < c) {
    j0 = cidx[cb + lane];
    float v = (si + nv[j0]) * cmval[cb + lane];
    e0 = v > 0.f ? v : LRELU_ALPHA * v;
  }
  if (lane + 64 < c) {
    j1 = cidx[cb + lane + 64];
    float v = (si + nv[j1]) * cmval[cb + lane + 64];
    e1 = v > 0.f ? v : LRELU_ALPHA * v;
  }
  float mx = fmaxf(e0, e1);
#pragma unroll
  for (int off = 32; off; off >>= 1) mx = fmaxf(mx, __shfl_xor(mx, off));
  float w0 = lane < c ? __expf(e0 - mx) : 0.f;
  float w1 = lane + 64 < c ? __expf(e1 - mx) : 0.f;
  float s = w0 + w1;
#pragma unroll
  for (int off = 32; off; off >>= 1) s += __shfl_xor(s, off);
  const float inv = 1.f / s;
  ws[wv][lane] = w0 * inv;
  ws[wv][lane + 64] = w1 * inv;
  js[wv][lane] = j0;
  js[wv][lane + 64] = j1;
  // intra-wave LDS write->read: single-wave coherence, no barrier
  const int cbase = half * CW;
  float acc[NQ];
#pragma unroll
  for (int q = 0; q < NQ; ++q) acc[q] = 0.f;
  if (BF16G) {
#pragma unroll 8
    for (int k = 0; k < c; ++k) {
      const float wk = ws[wv][k];
      const uint32_t* hr = (const uint32_t*)(hb + (size_t)js[wv][k] * D + cbase);
      uint32_t v = hr[lane];
      acc[0] = fmaf(wk, __uint_as_float(v << 16), acc[0]);
      acc[1] = fmaf(wk, __uint_as_float(v & 0xffff0000u), acc[1]);
    }
    float2 o;
    o.x = acc[0] > 0.f ? acc[0] : expm1f(acc[0]);
    o.y = acc[1] > 0.f ? acc[1] : expm1f(acc[1]);
    *(float2*)(out + (size_t)row * D + cbase + lane * 2) = o;
  } else {
#pragma unroll 8
    for (int k = 0; k < c; ++k) {
      const float wk = ws[wv][k];
      const float* hr = h + (size_t)js[wv][k] * D + cbase;
#pragma unroll
      for (int q = 0; q < NQ; ++q) acc[q] = fmaf(wk, hr[lane + q * 64], acc[q]);
    }
    if (!NORM) {
#pragma unroll
      for (int q = 0; q < NQ; ++q) {
        float a = acc[q];
        out[(size_t)row * D + cbase + lane + q * 64] = a > 0.f ? a : expm1f(a);
      }
    } else {
      float a = acc[0];
      a = a > 0.f ? a : expm1f(a);
      float sq = a * a;
#pragma unroll
      for (int off = 32; off; off >>= 1) sq += __shfl_xor(sq, off);
      float zv = a / fmaxf(sqrtf(sq), 1e-12f);
      out[(size_t)row * 64 + lane] = zv;
      zb[(size_t)row * 64 + lane] = (__bf16)zv;
    }
  }
}

// ---------------- A_pred = sigmoid(z @ z^T) via bf16 MFMA
__global__ __launch_bounds__(256) void decoder_mfma(const __bf16* __restrict__ zb,
                                                    float* __restrict__ out) {
  const int wv = threadIdx.x >> 6, lane = threadIdx.x & 63;
  const int ib = blockIdx.y * 64 + (wv >> 1) * 32;
  const int jb = blockIdx.x * 64 + (wv & 1) * 32;
  const int l31 = lane & 31, lh = lane >> 5;
  const __bf16* Arow = zb + (size_t)(ib + l31) * 64 + lh * 8;
  const __bf16* Brow = zb + (size_t)(jb + l31) * 64 + lh * 8;
  f32x16 acc;
#pragma unroll
  for (int r = 0; r < 16; ++r) acc[r] = 0.f;
#pragma unroll
  for (int kk = 0; kk < 4; ++kk) {
    bf16x8 af = *(const bf16x8*)(Arow + kk * 16);
    bf16x8 bfv = *(const bf16x8*)(Brow + kk * 16);
    acc = __builtin_amdgcn_mfma_f32_32x32x16_bf16(af, bfv, acc, 0, 0, 0);
  }
#pragma unroll
  for (int r = 0; r < 16; ++r) {
    int rowi = (r & 3) + 8 * (r >> 2) + 4 * lh;
    float v = 1.f / (1.f + __expf(-acc[r]));
    out[(size_t)(ib + rowi) * NROW + jb + l31] = v;
  }
}

extern "C" void kernel_launch(void* const* d_in, const int* in_sizes, int n_in,
                              void* d_out, int out_size, void* d_ws, size_t ws_size,
                              hipStream_t stream) {
  const float* x   = (const float*)d_in[0];
  const float* adj = (const float*)d_in[1];
  const float* Mm  = (const float*)d_in[2];
  const float* W1  = (const float*)d_in[3];
  const float* as1 = (const float*)d_in[4];
  const float* an1 = (const float*)d_in[5];
  const float* W2  = (const float*)d_in[6];
  const float* as2 = (const float*)d_in[7];
  const float* an2 = (const float*)d_in[8];
  const float* W3  = (const float*)d_in[9];
  const float* as3 = (const float*)d_in[10];
  const float* an3 = (const float*)d_in[11];

  float* out = (float*)d_out;
  float* z = out + (size_t)NROW * NROW;

  float* wsp = (float*)d_ws;
  float* hA   = wsp;                          // [N,256] (f32, layer-3 gather)
  float* hB   = hA + (size_t)NROW * 256;      // [N,256] (attn outputs)
  float* sv   = hB + (size_t)NROW * 256;      // [N]
  float* nv   = sv + NROW;                    // [N]
  float* cmv  = nv + NROW;                    // [N,MAXD]
  int*   cix  = (int*)(cmv + (size_t)NROW * MAXD);  // [N,MAXD]
  int*   cct  = cix + (size_t)NROW * MAXD;    // [N]
  __bf16* zb  = (__bf16*)(cct + NROW);        // [N,64]
  __bf16* w1h = zb + (size_t)NROW * 64;       // split/transposed weights
  __bf16* w1l = w1h + 512 * 256;
  __bf16* w2h = w1l + 512 * 256;
  __bf16* w2l = w2h + 256 * 128;
  __bf16* w3h = w2l + 256 * 128;
  __bf16* w3l = w3h + 128 * 64;
  float* wsa1 = (float*)(w3l + 128 * 64);     // wsa/wna vectors
  float* wna1 = wsa1 + 512;
  float* wsa2 = wna1 + 512;
  float* wna2 = wsa2 + 256;
  float* wsa3 = wna2 + 256;
  float* wna3 = wsa3 + 128;
  __bf16* hAb = (__bf16*)(wna3 + 128);        // [N,256] bf16 gather copy
  uint32_t* bmp = (uint32_t*)(hAb + (size_t)NROW * 256);  // [N,256] adj bitmap

  dim3 b256(256);

  // 1. prep: bitmap scan + weight splits + wsa/wna dots
  prep_scan<<<dim3(NROW + 676), b256, 0, stream>>>(
      adj, bmp, W1, W2, W3, w1h, w1l, w2h, w2l, w3h, w3l,
      as1, an1, as2, an2, as3, an3, wsa1, wna1, wsa2, wna2, wsa3, wna3);

  // 2. CSR from bitmap (+ M gather)
  csr_from_bitmap<<<dim3(NROW), b256, 0, stream>>>(bmp, Mm, cct, cix, cmv);

  // 3-4. Layer 1: LDS-staged split-K gemm (1536 blocks) -> attn
  gemm_lds2<<<dim3(NROW / 32, 256 / 32), b256, 0, stream>>>(x, w1h, w1l, wsa1, wna1, sv, nv, nullptr, hAb, 512, 256);
  attn_csr<256, 2, true, false><<<dim3(NROW / 2), b256, 0, stream>>>(nullptr, hAb, cct, cix, cmv, sv, nv, hB, nullptr);

  // 5-6. Layer 2
  gemm_lds2<<<dim3(NROW / 32, 128 / 32), b256, 0, stream>>>(hB, w2h, w2l, wsa2, wna2, sv, nv, nullptr, hAb, 256, 128);
  attn_csr<128, 1, true, false><<<dim3(NROW / 4), b256, 0, stream>>>(nullptr, hAb, cct, cix, cmv, sv, nv, hB, nullptr);

  // 7-8. Layer 3 (f32 h for gather+norm)
  gemm_lds2<<<dim3(NROW / 32, 64 / 32), b256, 0, stream>>>(hB, w3h, w3l, wsa3, wna3, sv, nv, hA, nullptr, 128, 64);
  attn_csr<64, 1, false, true><<<dim3(NROW / 4), b256, 0, stream>>>(hA, nullptr, cct, cix, cmv, sv, nv, z, zb);

  // 9. Decoder
  decoder_mfma<<<dim3(NROW / 64, NROW / 64), b256, 0, stream>>>(zb, out);
}